// Round 7
// baseline (148.284 us; speedup 1.0000x reference)
//
#include <hip/hip_runtime.h>
#include <hip/hip_bf16.h>

// Problem constants (fixed by reference)
#define B_ 16
#define L_ 24
#define N_ 256
#define E_ 4096
#define T_ (B_ * L_)   // 384 graphs

// ws layout (floats). X (LSTM h) stored as packed bf16 (WX). Graph gather is
// a dense bf16 GEMM vs the shared 256x256 edge-multiplicity matrix (WAFRG).
constexpr int WP    = 0;
constexpr int WRQ   = WP + 4096;
constexpr int WRM   = WRQ + 4096;          // Q alone (rare sel==0 correction)
constexpr int WBIAS = WRM + 4096;          // biasv [256][64]
constexpr int WALPHA= WBIAS + 16384;       // (unused now, layout kept)
constexpr int WBETA = WALPHA + 256;
constexpr int WDINV = WBETA + 256;         // 1/max(cnt,1) [256]
constexpr int WSEL  = WDINV + 256;         // cnt>0 ? 1 : 0 [256]
constexpr int WSW   = WSEL + 256;          // sw0[256], sw1[256]
constexpr int WCNTF = WSW + 512;           // cnt as float [256]
constexpr int WCOLP = WCNTF + 256;         // (unused, layout kept)
constexpr int WROWS = WCOLP + 260;         // (unused, layout kept)
constexpr int WHFRAG= WROWS + 4096;        // (unused now — k_main builds own)
constexpr int WQFRAG= WHFRAG + 8192;       // RQ/P bf16 B-frags, 1024 x 16B
constexpr int WX    = WQFRAG + 4096;       // X bf16 [T][N][64] = 12.6 MB
constexpr int WAFRG = WX + 3145728;        // mult^T bf16 B-frags, 8192 x 16B

using bf16x8 = __attribute__((ext_vector_type(8))) short;   // 8 bf16 (4 VGPRs)
using f32x4  = __attribute__((ext_vector_type(4))) float;   // MFMA C/D

__device__ __forceinline__ float sigm(float x) { return 1.f / (1.f + __expf(-x)); }
__device__ __forceinline__ float tanh_(float x) { return 2.f / (1.f + __expf(-2.f * x)) - 1.f; }
__device__ __forceinline__ unsigned f2bf(float f) {   // RNE bf16 bits
    unsigned u = __float_as_uint(f);
    return (u + 0x7fffu + ((u >> 16) & 1u)) >> 16;
}

constexpr int HS = 72;      // h tile row stride in shorts (16B-aligned rows)
constexpr int NLSTM = 512;  // 8 seqs/block -> independent blocks co-resident

// ---- K_main: blocks 0..511 = LSTM, 8 seqs each, 4 waves, 24 KB LDS.
// Design (r4/r6 lessons): (1) independent blocks -> free-running barriers ->
// phase diversity per SIMD; (2) gate/trans work redistributed across all 64
// lanes via shfl_up(32) (lanes>=32 own only garbage C-rows; they take rows
// {2,3},{6,7}) so chip-wide gate VALU equals the 16-seq layout; (3) LDS 24 KB
// + launch_bounds(256,4) so 2-4 blocks/CU genuinely co-schedule. MFMA is
// computed on all 16 rows (8 garbage) — matrix pipe is <10% busy, free.
// Blocks 512..520 = prep for k_graph (tables, P/RQ frags, mult frags).
__global__ __launch_bounds__(256, 4) void k_main(
    const float* __restrict__ aqi, const int* __restrict__ conn,
    const float* __restrict__ cw, const float* __restrict__ Wih,
    const float* __restrict__ embW, const float* __restrict__ embB,
    const float* __restrict__ bih, const float* __restrict__ bhh,
    const float* __restrict__ Whh, const float* __restrict__ m1W,
    const float* __restrict__ m1b, const float* __restrict__ m2W,
    const float* __restrict__ m2b, float* __restrict__ ws) {
    __shared__ __align__(16) char smem[24576];
    int t = threadIdx.x, blk = blockIdx.x;

    if (blk >= NLSTM) {
        int role = blk - NLSTM;
        if (role == 0) {
            // ---- tables: histogram, dinv/sel/sw/cntf, bias ----
            int* s_cnt   = (int*)smem;
            float* s_sw0 = (float*)(smem + 1024);
            float* s_sw1 = (float*)(smem + 2048);
            float* sU    = (float*)(smem + 3072);
            s_cnt[t] = 0; s_sw0[t] = 0.f; s_sw1[t] = 0.f;
            __syncthreads();
            for (int e = t; e < E_; e += 256) {
                int c = conn[E_ + e] & 255;
                atomicAdd(&s_cnt[c], 1);
                atomicAdd(&s_sw0[c], cw[2 * e]);
                atomicAdd(&s_sw1[c], cw[2 * e + 1]);
            }
            __syncthreads();
            int cnt = s_cnt[t];
            ws[WCNTF + t] = (float)cnt;
            ws[WDINV + t] = 1.f / (float)(cnt > 1 ? cnt : 1);
            ws[WSEL + t]  = cnt > 0 ? 1.f : 0.f;
            ws[WSW + t]        = s_sw0[t];
            ws[WSW + N_ + t]   = s_sw1[t];
            if (t < 192) {
                int part = t >> 6, j = t & 63;
                float acc = 0.f;
                #pragma unroll 8
                for (int m = 0; m < 64; ++m) {
                    float w = (part == 0) ? m1W[128 * 64 + m]
                            : (part == 1) ? m1W[129 * 64 + m] : m1b[m];
                    acc = fmaf(w, m2W[(64 + m) * 64 + j], acc);
                }
                sU[part * 64 + j] = acc;
            }
            __syncthreads();
            {
                int j = t & 63;
                float u0 = sU[j], u1 = sU[64 + j], u2 = sU[128 + j];
                float b2j = m2b[j];
                int vb = t >> 6;
                #pragma unroll 8
                for (int i = 0; i < 64; ++i) {
                    int v = vb + i * 4;
                    int cv = s_cnt[v];
                    float dv = 1.f / (float)(cv > 1 ? cv : 1);
                    float bb = s_sw0[v] * u0 + s_sw1[v] * u1 + (float)cv * u2;
                    ws[WBIAS + v * 64 + j] = dv * bb + b2j;
                }
            }
            return;
        }
        if (role <= 4) {
            // ---- P/RQ halves -> B-frags. role 1,2: P ks=0,1; 3,4: RQ ----
            float* sB = (float*)smem;            // 16 KB: W2b
            float* sM = (float*)(smem + 16384);  // 8 KB
            int mi = role - 1;
            bool isP = mi < 2;
            int ks = mi & 1;
            #pragma unroll
            for (int i = 0; i < 16; ++i) sB[t + 256 * i] = m2W[64 * 64 + t + 256 * i];
            __syncthreads();
            int j = t & 63, kl = t >> 6;
            for (int r = 0; r < 8; ++r) {
                int kk = kl * 8 + r;
                int k = ks * 32 + kk;
                const float* arow = m1W + (isP ? k : (64 + k)) * 64;
                float acc = 0.f;
                #pragma unroll
                for (int m = 0; m < 64; m += 4) {
                    float4 a4 = *(const float4*)(arow + m);
                    acc = fmaf(a4.x, sB[m * 64 + j], acc);
                    acc = fmaf(a4.y, sB[(m + 1) * 64 + j], acc);
                    acc = fmaf(a4.z, sB[(m + 2) * 64 + j], acc);
                    acc = fmaf(a4.w, sB[(m + 3) * 64 + j], acc);
                }
                if (isP) {
                    sM[kk * 64 + j] = acc;
                } else {
                    ws[WRM + k * 64 + j] = acc;
                    sM[kk * 64 + j] = acc + m2W[k * 64 + j];
                }
            }
            __syncthreads();
            {
                int ct = t >> 6, l = t & 63;
                int fi = (isP ? 8 : 0) + ks * 4 + ct;
                int rb = (l >> 4) * 8;
                int n = ct * 16 + (l & 15);
                unsigned uu[4];
                #pragma unroll
                for (int q = 0; q < 4; ++q)
                    uu[q] = f2bf(sM[(rb + 2 * q) * 64 + n])
                          | (f2bf(sM[(rb + 2 * q + 1) * 64 + n]) << 16);
                ((uint4*)(ws + WQFRAG))[fi * 64 + l] = make_uint4(uu[0], uu[1], uu[2], uu[3]);
            }
            return;
        }
        // ---- roles 5..8: one v-quarter of mult-matrix B-frags (16 KB hist) --
        unsigned* Mw = (unsigned*)smem;   // 64 v x 64 words = 16 KB
        int qd = role - 5;                // v in [qd*64, qd*64+64)
        for (int i = t; i < 64 * 64; i += 256) Mw[i] = 0u;
        __syncthreads();
        for (int e = t; e < E_; e += 256) {
            int k = conn[e] & 255;
            int v = conn[E_ + e] & 255;
            if ((v >> 6) == qd)
                atomicAdd(&Mw[(v & 63) * 64 + (k >> 2)], 1u << ((k & 3) * 8));
        }
        __syncthreads();
        uint4* dst = (uint4*)(ws + WAFRG);
        int base = qd * 2048;
        #pragma unroll
        for (int u0 = 0; u0 < 8; ++u0) {
            int u = base + u0 * 256 + t;      // frag words for nt in quarter
            int fi = u >> 6, l = u & 63;
            int nt = fi >> 3, ks = fi & 7;
            int v = nt * 16 + (l & 15);
            int kb = ks * 8 + ((l >> 4) << 1);
            unsigned w0 = Mw[(v & 63) * 64 + kb];
            unsigned w1 = Mw[(v & 63) * 64 + kb + 1];
            unsigned uu[4];
            #pragma unroll
            for (int q = 0; q < 2; ++q) {
                unsigned c0 = (w0 >> (q * 16)) & 255u;
                unsigned c1 = (w0 >> (q * 16 + 8)) & 255u;
                uu[q] = f2bf((float)c0) | (f2bf((float)c1) << 16);
                unsigned d0 = (w1 >> (q * 16)) & 255u;
                unsigned d1 = (w1 >> (q * 16 + 8)) & 255u;
                uu[2 + q] = f2bf((float)d0) | (f2bf((float)d1) << 16);
            }
            dst[u] = make_uint4(uu[0], uu[1], uu[2], uu[3]);
        }
        return;
    }

    // ---------------- LSTM (blocks 0..511, 8 seqs, 4 waves) ----------------
    short* sHhi = (short*)smem;                       // [2][16*HS]
    short* sHlo = (short*)(smem + 4608);
    float* sX   = (float*)(smem + 9216);              // [24][16] (cols 8-15 = 0)
    int w = t >> 6, lane = t & 63;
    int seq0 = blk * 8;
    int b0 = seq0 >> 8, n0 = seq0 & 255;
    int c0 = lane & 15, quad = lane >> 4, q4 = quad * 4, q8 = quad * 8;
    bool hiHalf = lane >= 32;
    int r0 = hiHalf ? (q4 - 6) : q4;      // lanes<32: rows {0,1},{4,5}; >=32: {2,3},{6,7}
    // zero-init h exchange buffers (garbage rows stay finite)
    {
        uint4* z = (uint4*)smem;
        #pragma unroll
        for (int i = 0; i < 3; ++i)
            if (t + 256 * i < 576) z[t + 256 * i] = make_uint4(0, 0, 0, 0);
    }
    // self-built wave-private W_hh fragments (ct = 4g+w, ks = 0/1)
    bf16x8 wreg[4][2];
    #pragma unroll
    for (int g = 0; g < 4; ++g) {
        int ct = 4 * g + w;
        #pragma unroll
        for (int ks = 0; ks < 2; ++ks) {
            const float* src = Whh + (ct * 16 + c0) * 64 + ks * 32 + q8;
            union { bf16x8 v; unsigned u[4]; } tmp;
            #pragma unroll
            for (int q = 0; q < 4; ++q)
                tmp.u[q] = f2bf(src[2 * q]) | (f2bf(src[2 * q + 1]) << 16);
            wreg[g][ks] = tmp.v;
        }
    }
    for (int i = t; i < 384; i += 256) {
        int l = i >> 4, c = i & 15;
        sX[l * 16 + c] = (c < 8) ? aqi[(b0 * L_ + l) * N_ + n0 + c] : 0.f;
    }
    // self-built alpha/beta (bit-identical arithmetic order)
    float alF[4], beF[4];
    #pragma unroll
    for (int g = 0; g < 4; ++g) {
        int tp = (4 * g + w) * 16 + c0;
        float a = 0.f, b = 0.f;
        #pragma unroll
        for (int i = 0; i < 16; ++i) {
            float wv = Wih[tp * 16 + i];
            a += wv * embW[i];
            b += wv * embB[i];
        }
        alF[g] = a;
        beF[g] = b + bih[tp] + bhh[tp];
    }
    unsigned short* xws = (unsigned short*)(ws + WX);
    float cst[2] = {0.f, 0.f};
    bf16x8 hA[2][2] = {};
    __syncthreads();
    for (int l = 0; l < L_; ++l) {
        int buf = l & 1;
        f32x4 acc[4];
        #pragma unroll
        for (int g = 0; g < 4; ++g) {
            #pragma unroll
            for (int r = 0; r < 4; ++r)
                acc[g][r] = fmaf(sX[l * 16 + q4 + r], alF[g], beF[g]);
        }
        if (l > 0) {
            #pragma unroll
            for (int g = 0; g < 4; ++g) {
                #pragma unroll
                for (int ks = 0; ks < 2; ++ks) {
                    acc[g] = __builtin_amdgcn_mfma_f32_16x16x32_bf16(
                        hA[0][ks], wreg[g][ks], acc[g], 0, 0, 0);
                    acc[g] = __builtin_amdgcn_mfma_f32_16x16x32_bf16(
                        hA[1][ks], wreg[g][ks], acc[g], 0, 0, 0);
                }
            }
        }
        // redistribute valid rows across all 64 lanes: lanes>=32 take the
        // (row 2,3 / 6,7) values from their partner lane-32 (same col).
        float ga[4][2];
        #pragma unroll
        for (int g = 0; g < 4; ++g) {
            float v2 = __shfl_up(acc[g][2], 32);
            float v3 = __shfl_up(acc[g][3], 32);
            ga[g][0] = hiHalf ? v2 : acc[g][0];
            ga[g][1] = hiHalf ? v3 : acc[g][1];
        }
        #pragma unroll
        for (int rr = 0; rr < 2; ++rr) {
            float iv = sigm(ga[0][rr]);
            float fv = sigm(ga[1][rr]);
            float gv = tanh_(ga[2][rr]);
            float ov = sigm(ga[3][rr]);
            cst[rr] = fmaf(fv, cst[rr], iv * gv);
            float h = ov * tanh_(cst[rr]);
            unsigned hb = f2bf(h);
            float hf = __uint_as_float(hb << 16);
            unsigned lb = f2bf(h - hf);
            int r = r0 + rr;
            sHhi[buf * (16 * HS) + r * HS + w * 16 + c0] = (short)hb;
            sHlo[buf * (16 * HS) + r * HS + w * 16 + c0] = (short)lb;
        }
        // raw barrier: drain LDS only (lgkm), NOT the global X-store (vmcnt).
        asm volatile("s_waitcnt lgkmcnt(0)" ::: "memory");
        __builtin_amdgcn_s_barrier();
        hA[0][0] = *(const bf16x8*)&sHhi[buf * (16 * HS) + c0 * HS + q8];
        hA[0][1] = *(const bf16x8*)&sHhi[buf * (16 * HS) + c0 * HS + 32 + q8];
        hA[1][0] = *(const bf16x8*)&sHlo[buf * (16 * HS) + c0 * HS + q8];
        hA[1][1] = *(const bf16x8*)&sHlo[buf * (16 * HS) + c0 * HS + 32 + q8];
        // coalesced X write (bf16 hi bits straight out of LDS): 8 valid rows.
        if (t < 128) {
            int row = t >> 4, ch = t & 15;
            uint2 xa = *(const uint2*)&sHhi[buf * (16 * HS) + row * HS + ch * 4];
            *(uint2*)(xws + ((size_t)(b0 * L_ + l) * N_ + n0) * 64 + row * 64 + ch * 4) = xa;
        }
    }
}

// ------- K_graph: all-MFMA GNN ---------------------------------------------
// GEMM1: S'^T = X^T @ mult^T (A-frags gathered from Xl, B-frags streamed),
// dinv applied in f32. GEMM2: out = bias + X@RQ + Sl@P.
constexpr int XS = 72;   // bf16 LDS row stride (16B-aligned rows)

__global__ __launch_bounds__(256, 2) void k_graph(
    const float* __restrict__ ws, float* __restrict__ out) {
    __shared__ __align__(16) short Xl[N_ * XS];   // 36.9 KB
    __shared__ __align__(16) short Sl[N_ * XS];   // 36.9 KB
    int tg = blockIdx.x;
    int tid = threadIdx.x;
    int lane = tid & 63, w = tid >> 6;
    int c0 = lane & 15, quad = lane >> 4, q8 = quad * 8;
    const uint4* src = (const uint4*)((const unsigned short*)(ws + WX)
                                      + (size_t)tg * (N_ * 64));
    #pragma unroll
    for (int it = 0; it < 8; ++it) {
        int idx = tid + it * 256;
        uint4 d = src[idx];
        int node = idx >> 3, q = idx & 7;
        *(uint4*)&Xl[node * XS + q * 8] = d;
    }
    float dv[16];
    #pragma unroll
    for (int nt = 0; nt < 16; ++nt) dv[nt] = ws[WDINV + nt * 16 + c0];
    __syncthreads();
    // ---- GEMM1: wave w owns j-tile mt=w; A-frags via broadcast-pair b32 ----
    bf16x8 af[8];
    {
        int colb = w * 16 + (c0 & 14);
        int sh = (c0 & 1) * 16;
        int rbase = (lane >> 4) * 8;
        #pragma unroll
        for (int ks = 0; ks < 8; ++ks) {
            unsigned wd[8];
            #pragma unroll
            for (int j = 0; j < 8; ++j)
                wd[j] = *(const unsigned*)&Xl[(ks * 32 + rbase + j) * XS + colb];
            union { bf16x8 v; unsigned u[4]; } tmp;
            #pragma unroll
            for (int q = 0; q < 4; ++q)
                tmp.u[q] = ((wd[2 * q] >> sh) & 0xffffu)
                         | (((wd[2 * q + 1] >> sh) & 0xffffu) << 16);
            af[ks] = tmp.v;
        }
    }
    f32x4 acc[16];
    #pragma unroll
    for (int nt = 0; nt < 16; ++nt) {
        #pragma unroll
        for (int r = 0; r < 4; ++r) acc[nt][r] = 0.f;
    }
    {
        const bf16x8* bsrc = (const bf16x8*)(ws + WAFRG);
        #pragma unroll
        for (int nt = 0; nt < 16; ++nt) {
            bf16x8 bf[8];
            #pragma unroll
            for (int ks = 0; ks < 8; ++ks)
                bf[ks] = bsrc[(nt * 8 + ks) * 64 + lane];
            #pragma unroll
            for (int ks = 0; ks < 8; ++ks)
                acc[nt] = __builtin_amdgcn_mfma_f32_16x16x32_bf16(
                    af[ks], bf[ks], acc[nt], 0, 0, 0);
        }
    }
    {
        int j0 = w * 16 + quad * 4;
        #pragma unroll
        for (int nt = 0; nt < 16; ++nt) {
            float d = dv[nt];
            unsigned p0 = f2bf(acc[nt][0] * d) | (f2bf(acc[nt][1] * d) << 16);
            unsigned p1 = f2bf(acc[nt][2] * d) | (f2bf(acc[nt][3] * d) << 16);
            int v = nt * 16 + c0;
            *(uint2*)&Sl[v * XS + j0] = make_uint2(p0, p1);
        }
    }
    __syncthreads();
    // ---- GEMM2: wave w owns row-tiles 4w..4w+3 ----
    bf16x8 bq[16];
    {
        const bf16x8* qf = (const bf16x8*)(ws + WQFRAG);
        #pragma unroll
        for (int i = 0; i < 16; ++i) bq[i] = qf[i * 64 + lane];
    }
    const float* bias = ws + WBIAS;
    #pragma unroll
    for (int rti = 0; rti < 4; ++rti) {
        int rt = w * 4 + rti;
        const short* xr = &Xl[(rt * 16 + c0) * XS];
        const short* sr = &Sl[(rt * 16 + c0) * XS];
        bf16x8 ax0 = *(const bf16x8*)(xr + q8);
        bf16x8 ax1 = *(const bf16x8*)(xr + 32 + q8);
        bf16x8 as0 = *(const bf16x8*)(sr + q8);
        bf16x8 as1 = *(const bf16x8*)(sr + 32 + q8);
        #pragma unroll
        for (int ct = 0; ct < 4; ++ct) {
            f32x4 a2;
            #pragma unroll
            for (int r = 0; r < 4; ++r)
                a2[r] = bias[(rt * 16 + quad * 4 + r) * 64 + ct * 16 + c0];
            a2 = __builtin_amdgcn_mfma_f32_16x16x32_bf16(ax0, bq[ct],      a2, 0, 0, 0);
            a2 = __builtin_amdgcn_mfma_f32_16x16x32_bf16(ax1, bq[4 + ct],  a2, 0, 0, 0);
            a2 = __builtin_amdgcn_mfma_f32_16x16x32_bf16(as0, bq[8 + ct],  a2, 0, 0, 0);
            a2 = __builtin_amdgcn_mfma_f32_16x16x32_bf16(as1, bq[12 + ct], a2, 0, 0, 0);
            #pragma unroll
            for (int r = 0; r < 4; ++r)
                out[((size_t)tg * 256 + rt * 16 + quad * 4 + r) * 64 + ct * 16 + c0]
                    = a2[r];
        }
    }
    // ---- rare correction (cnt==0 -> W2a, not W2a+Q) ----
    int v = tid;
    float sel = ws[WSEL + v];
    if (__syncthreads_or(sel < 0.5f)) {
        if (sel < 0.5f) {
            float* og = out + ((size_t)tg * 256 + v) * 64;
            #pragma unroll
            for (int jc = 0; jc < 4; ++jc) {
                float corr[16];
                #pragma unroll
                for (int j = 0; j < 16; ++j) corr[j] = 0.f;
                #pragma unroll
                for (int k = 0; k < 64; ++k) {
                    unsigned hv = (unsigned short)Xl[v * XS + k];
                    float xk = __uint_as_float(hv << 16);
                    const float* Q = ws + WRM + k * 64 + jc * 16;
                    #pragma unroll
                    for (int j = 0; j < 16; ++j) corr[j] += xk * Q[j];
                }
                #pragma unroll
                for (int j = 0; j < 16; ++j) og[jc * 16 + j] -= corr[j];
            }
        }
    }
}

extern "C" void kernel_launch(void* const* d_in, const int* in_sizes, int n_in,
                              void* d_out, int out_size, void* d_ws, size_t ws_size,
                              hipStream_t stream) {
    const float* aqi  = (const float*)d_in[0];
    const int*   conn = (const int*)d_in[1];
    const float* cw   = (const float*)d_in[2];
    const float* embW = (const float*)d_in[3];
    const float* embB = (const float*)d_in[4];
    const float* Wih  = (const float*)d_in[5];
    const float* Whh  = (const float*)d_in[6];
    const float* bih  = (const float*)d_in[7];
    const float* bhh  = (const float*)d_in[8];
    const float* m1W  = (const float*)d_in[9];
    const float* m1b  = (const float*)d_in[10];
    const float* m2W  = (const float*)d_in[11];
    const float* m2b  = (const float*)d_in[12];
    float* ws  = (float*)d_ws;
    float* out = (float*)d_out;

    k_main<<<dim3(NLSTM + 9), dim3(256), 0, stream>>>(aqi, conn, cw, Wih, embW,
                                                      embB, bih, bhh, Whh, m1W,
                                                      m1b, m2W, m2b, ws);
    k_graph<<<dim3(T_), dim3(256), 0, stream>>>(ws, out);
}

// Round 8
// 134.275 us; speedup vs baseline: 1.1043x; 1.1043x over previous
//
#include <hip/hip_runtime.h>
#include <hip/hip_bf16.h>

// Problem constants (fixed by reference)
#define B_ 16
#define L_ 24
#define N_ 256
#define E_ 4096
#define T_ (B_ * L_)   // 384 graphs

// ws layout (floats). X (LSTM h) stored as packed bf16 (WX). Graph gather is
// a dense bf16 GEMM vs the shared 256x256 edge-multiplicity matrix (WAFRG).
constexpr int WP    = 0;
constexpr int WRQ   = WP + 4096;
constexpr int WRM   = WRQ + 4096;          // Q alone (rare sel==0 correction)
constexpr int WBIAS = WRM + 4096;          // biasv [256][64]
constexpr int WALPHA= WBIAS + 16384;       // (unused now, layout kept)
constexpr int WBETA = WALPHA + 256;
constexpr int WDINV = WBETA + 256;         // 1/max(cnt,1) [256]
constexpr int WSEL  = WDINV + 256;         // cnt>0 ? 1 : 0 [256]
constexpr int WSW   = WSEL + 256;          // sw0[256], sw1[256]
constexpr int WCNTF = WSW + 512;           // cnt as float [256]
constexpr int WCOLP = WCNTF + 256;         // (unused, layout kept)
constexpr int WROWS = WCOLP + 260;         // (unused, layout kept)
constexpr int WHFRAG= WROWS + 4096;        // (unused now — k_main builds own)
constexpr int WQFRAG= WHFRAG + 8192;       // RQ/P bf16 B-frags, 1024 x 16B
constexpr int WX    = WQFRAG + 4096;       // X bf16 [T][N][64] = 12.6 MB
constexpr int WAFRG = WX + 3145728;        // mult^T bf16 B-frags, 8192 x 16B

using bf16x8 = __attribute__((ext_vector_type(8))) short;   // 8 bf16 (4 VGPRs)
using f32x4  = __attribute__((ext_vector_type(4))) float;   // MFMA C/D

// Gate math on the 24-step serial chain: use raw v_rcp_f32 (1 ULP) instead of
// the IEEE div sequence (div_scale/rcp/div_fmas/div_fixup ~12 ops, 2 trans).
// 20 divisions/lane/step were on the critical path; rcp error (~1e-7 rel) is
// 4 orders below the bf16 rounding this pipeline already carries.
__device__ __forceinline__ float rcp_(float x) { return __builtin_amdgcn_rcpf(x); }
__device__ __forceinline__ float sigm(float x) { return rcp_(1.f + __expf(-x)); }
__device__ __forceinline__ float tanh_(float x) {
    return fmaf(2.f, rcp_(1.f + __expf(-2.f * x)), -1.f);
}
__device__ __forceinline__ unsigned f2bf(float f) {   // RNE bf16 bits
    unsigned u = __float_as_uint(f);
    return (u + 0x7fffu + ((u >> 16) & 1u)) >> 16;
}

constexpr int HS = 72;   // h tile row stride in shorts (16B-aligned rows)

// ---- K_main: blocks 0..255 = LSTM (16 seqs each; self-sufficient prologue).
// Blocks 256..264 = prep for k_graph only (tables, P/RQ frags, mult frags) —
// runs CONCURRENTLY with the LSTM.
// k_main wall time == ONE block's 24-step chain (proven r3/r6/r7: invariant
// to occupancy) — so only per-step critical-path cuts help. Step barrier is
// raw lgkmcnt(0)+s_barrier (no vmcnt drain of the X-store).
__global__ __launch_bounds__(256, 2) void k_main(
    const float* __restrict__ aqi, const int* __restrict__ conn,
    const float* __restrict__ cw, const float* __restrict__ Wih,
    const float* __restrict__ embW, const float* __restrict__ embB,
    const float* __restrict__ bih, const float* __restrict__ bhh,
    const float* __restrict__ Whh, const float* __restrict__ m1W,
    const float* __restrict__ m1b, const float* __restrict__ m2W,
    const float* __restrict__ m2b, float* __restrict__ ws) {
    __shared__ __align__(16) char smem[65536];
    int t = threadIdx.x, blk = blockIdx.x;

    if (blk >= 256) {
        int role = blk - 256;
        if (role == 0) {
            // ---- tables: histogram, dinv/sel/sw/cntf, bias ----
            int* s_cnt   = (int*)smem;
            float* s_sw0 = (float*)(smem + 1024);
            float* s_sw1 = (float*)(smem + 2048);
            float* sU    = (float*)(smem + 3072);
            s_cnt[t] = 0; s_sw0[t] = 0.f; s_sw1[t] = 0.f;
            __syncthreads();
            for (int e = t; e < E_; e += 256) {
                int c = conn[E_ + e] & 255;
                atomicAdd(&s_cnt[c], 1);
                atomicAdd(&s_sw0[c], cw[2 * e]);
                atomicAdd(&s_sw1[c], cw[2 * e + 1]);
            }
            __syncthreads();
            int cnt = s_cnt[t];
            ws[WCNTF + t] = (float)cnt;
            ws[WDINV + t] = 1.f / (float)(cnt > 1 ? cnt : 1);
            ws[WSEL + t]  = cnt > 0 ? 1.f : 0.f;
            ws[WSW + t]        = s_sw0[t];
            ws[WSW + N_ + t]   = s_sw1[t];
            if (t < 192) {
                int part = t >> 6, j = t & 63;
                float acc = 0.f;
                #pragma unroll 8
                for (int m = 0; m < 64; ++m) {
                    float w = (part == 0) ? m1W[128 * 64 + m]
                            : (part == 1) ? m1W[129 * 64 + m] : m1b[m];
                    acc = fmaf(w, m2W[(64 + m) * 64 + j], acc);
                }
                sU[part * 64 + j] = acc;
            }
            __syncthreads();
            {
                int j = t & 63;
                float u0 = sU[j], u1 = sU[64 + j], u2 = sU[128 + j];
                float b2j = m2b[j];
                int vb = t >> 6;
                #pragma unroll 8
                for (int i = 0; i < 64; ++i) {
                    int v = vb + i * 4;
                    int cv = s_cnt[v];
                    float dv = 1.f / (float)(cv > 1 ? cv : 1);
                    float bb = s_sw0[v] * u0 + s_sw1[v] * u1 + (float)cv * u2;
                    ws[WBIAS + v * 64 + j] = dv * bb + b2j;
                }
            }
            return;
        }
        if (role <= 4) {
            // ---- P/RQ halves -> B-frags. role 1,2: P ks=0,1; 3,4: RQ ----
            float* sB = (float*)smem;            // 16 KB: W2b
            float* sM = (float*)(smem + 16384);  // 8 KB
            int mi = role - 1;
            bool isP = mi < 2;
            int ks = mi & 1;
            #pragma unroll
            for (int i = 0; i < 16; ++i) sB[t + 256 * i] = m2W[64 * 64 + t + 256 * i];
            __syncthreads();
            int j = t & 63, kl = t >> 6;
            for (int r = 0; r < 8; ++r) {
                int kk = kl * 8 + r;
                int k = ks * 32 + kk;
                const float* arow = m1W + (isP ? k : (64 + k)) * 64;
                float acc = 0.f;
                #pragma unroll
                for (int m = 0; m < 64; m += 4) {
                    float4 a4 = *(const float4*)(arow + m);
                    acc = fmaf(a4.x, sB[m * 64 + j], acc);
                    acc = fmaf(a4.y, sB[(m + 1) * 64 + j], acc);
                    acc = fmaf(a4.z, sB[(m + 2) * 64 + j], acc);
                    acc = fmaf(a4.w, sB[(m + 3) * 64 + j], acc);
                }
                if (isP) {
                    sM[kk * 64 + j] = acc;
                } else {
                    ws[WRM + k * 64 + j] = acc;
                    sM[kk * 64 + j] = acc + m2W[k * 64 + j];
                }
            }
            __syncthreads();
            {
                int ct = t >> 6, l = t & 63;
                int fi = (isP ? 8 : 0) + ks * 4 + ct;
                int rb = (l >> 4) * 8;
                int n = ct * 16 + (l & 15);
                unsigned uu[4];
                #pragma unroll
                for (int q = 0; q < 4; ++q)
                    uu[q] = f2bf(sM[(rb + 2 * q) * 64 + n])
                          | (f2bf(sM[(rb + 2 * q + 1) * 64 + n]) << 16);
                ((uint4*)(ws + WQFRAG))[fi * 64 + l] = make_uint4(uu[0], uu[1], uu[2], uu[3]);
            }
            return;
        }
        // ---- roles 5..8: mult-matrix B-frags (rebuild 64 KB histogram) ----
        unsigned* Mw = (unsigned*)smem;   // 64 KB
        for (int i = t; i < 256 * 64; i += 256) Mw[i] = 0u;
        __syncthreads();
        for (int e = t; e < E_; e += 256) {
            int k = conn[e] & 255;
            int v = conn[E_ + e] & 255;
            atomicAdd(&Mw[v * 64 + (k >> 2)], 1u << ((k & 3) * 8));
        }
        __syncthreads();
        uint4* dst = (uint4*)(ws + WAFRG);
        int base = (role - 5) * 2048;
        #pragma unroll
        for (int u0 = 0; u0 < 8; ++u0) {
            int u = base + u0 * 256 + t;      // 0..8191
            int fi = u >> 6, l = u & 63;
            int nt = fi >> 3, ks = fi & 7;
            int v = nt * 16 + (l & 15);
            int kb = ks * 8 + ((l >> 4) << 1);
            unsigned w0 = Mw[v * 64 + kb];
            unsigned w1 = Mw[v * 64 + kb + 1];
            unsigned uu[4];
            #pragma unroll
            for (int q = 0; q < 2; ++q) {
                unsigned c0 = (w0 >> (q * 16)) & 255u;
                unsigned c1 = (w0 >> (q * 16 + 8)) & 255u;
                uu[q] = f2bf((float)c0) | (f2bf((float)c1) << 16);
                unsigned d0 = (w1 >> (q * 16)) & 255u;
                unsigned d1 = (w1 >> (q * 16 + 8)) & 255u;
                uu[2 + q] = f2bf((float)d0) | (f2bf((float)d1) << 16);
            }
            dst[u] = make_uint4(uu[0], uu[1], uu[2], uu[3]);
        }
        return;
    }

    // ---------------- LSTM (blocks 0..255, 16 seqs each) ----------------
    short* sHhi = (short*)smem;                       // [2][16*HS]
    short* sHlo = (short*)(smem + 4608);
    float* sX   = (float*)(smem + 9216);              // [24][16]
    int w = t >> 6, lane = t & 63;
    int seq0 = blk * 16;
    int b0 = seq0 >> 8, n0 = seq0 & 255;
    int c0 = lane & 15, quad = lane >> 4, q4 = quad * 4, q8 = quad * 8;
    // self-built wave-private W_hh fragments (ct = 4g+w, ks = 0/1)
    bf16x8 wreg[4][2];
    #pragma unroll
    for (int g = 0; g < 4; ++g) {
        int ct = 4 * g + w;
        #pragma unroll
        for (int ks = 0; ks < 2; ++ks) {
            const float* src = Whh + (ct * 16 + c0) * 64 + ks * 32 + q8;
            union { bf16x8 v; unsigned u[4]; } tmp;
            #pragma unroll
            for (int q = 0; q < 4; ++q)
                tmp.u[q] = f2bf(src[2 * q]) | (f2bf(src[2 * q + 1]) << 16);
            wreg[g][ks] = tmp.v;
        }
    }
    for (int i = t; i < 384; i += 256) {
        int l = i >> 4, c = i & 15;
        sX[l * 16 + c] = aqi[(b0 * L_ + l) * N_ + n0 + c];
    }
    // self-built alpha/beta (bit-identical arithmetic order)
    float alF[4], beF[4];
    #pragma unroll
    for (int g = 0; g < 4; ++g) {
        int tp = (4 * g + w) * 16 + c0;
        float a = 0.f, b = 0.f;
        #pragma unroll
        for (int i = 0; i < 16; ++i) {
            float wv = Wih[tp * 16 + i];
            a += wv * embW[i];
            b += wv * embB[i];
        }
        alF[g] = a;
        beF[g] = b + bih[tp] + bhh[tp];
    }
    unsigned short* xws = (unsigned short*)(ws + WX);
    float cst[4] = {0.f, 0.f, 0.f, 0.f};
    bf16x8 hA[2][2] = {};
    __syncthreads();
    for (int l = 0; l < L_; ++l) {
        int buf = l & 1;
        f32x4 acc[4];
        #pragma unroll
        for (int g = 0; g < 4; ++g) {
            #pragma unroll
            for (int r = 0; r < 4; ++r)
                acc[g][r] = fmaf(sX[l * 16 + q4 + r], alF[g], beF[g]);
        }
        if (l > 0) {
            #pragma unroll
            for (int g = 0; g < 4; ++g) {
                #pragma unroll
                for (int ks = 0; ks < 2; ++ks) {
                    acc[g] = __builtin_amdgcn_mfma_f32_16x16x32_bf16(
                        hA[0][ks], wreg[g][ks], acc[g], 0, 0, 0);
                    acc[g] = __builtin_amdgcn_mfma_f32_16x16x32_bf16(
                        hA[1][ks], wreg[g][ks], acc[g], 0, 0, 0);
                }
            }
        }
        #pragma unroll
        for (int r = 0; r < 4; ++r) {
            float iv = sigm(acc[0][r]);
            float fv = sigm(acc[1][r]);
            float gv = tanh_(acc[2][r]);
            float ov = sigm(acc[3][r]);
            cst[r] = fmaf(fv, cst[r], iv * gv);
            float h = ov * tanh_(cst[r]);
            unsigned hb = f2bf(h);
            float hf = __uint_as_float(hb << 16);
            unsigned lb = f2bf(h - hf);
            sHhi[buf * (16 * HS) + (q4 + r) * HS + w * 16 + c0] = (short)hb;
            sHlo[buf * (16 * HS) + (q4 + r) * HS + w * 16 + c0] = (short)lb;
        }
        // raw barrier: drain LDS only (lgkm), NOT the global X-store (vmcnt).
        asm volatile("s_waitcnt lgkmcnt(0)" ::: "memory");
        __builtin_amdgcn_s_barrier();
        hA[0][0] = *(const bf16x8*)&sHhi[buf * (16 * HS) + c0 * HS + q8];
        hA[0][1] = *(const bf16x8*)&sHhi[buf * (16 * HS) + c0 * HS + 32 + q8];
        hA[1][0] = *(const bf16x8*)&sHlo[buf * (16 * HS) + c0 * HS + q8];
        hA[1][1] = *(const bf16x8*)&sHlo[buf * (16 * HS) + c0 * HS + 32 + q8];
        // coalesced X write (bf16 hi bits straight out of LDS)
        {
            int row = t >> 4, ch = t & 15;
            uint2 xa = *(const uint2*)&sHhi[buf * (16 * HS) + row * HS + ch * 4];
            *(uint2*)(xws + ((size_t)(b0 * L_ + l) * N_ + n0) * 64 + row * 64 + ch * 4) = xa;
        }
    }
}

// ------- K_graph: all-MFMA GNN ---------------------------------------------
// GEMM1: S'^T = X^T @ mult^T (A-frags gathered from Xl, B-frags streamed),
// dinv applied in f32. GEMM2: out = bias + X@RQ + Sl@P.
constexpr int XS = 72;   // bf16 LDS row stride (16B-aligned rows)

__global__ __launch_bounds__(256, 2) void k_graph(
    const float* __restrict__ ws, float* __restrict__ out) {
    __shared__ __align__(16) short Xl[N_ * XS];   // 36.9 KB
    __shared__ __align__(16) short Sl[N_ * XS];   // 36.9 KB
    int tg = blockIdx.x;
    int tid = threadIdx.x;
    int lane = tid & 63, w = tid >> 6;
    int c0 = lane & 15, quad = lane >> 4, q8 = quad * 8;
    const uint4* src = (const uint4*)((const unsigned short*)(ws + WX)
                                      + (size_t)tg * (N_ * 64));
    #pragma unroll
    for (int it = 0; it < 8; ++it) {
        int idx = tid + it * 256;
        uint4 d = src[idx];
        int node = idx >> 3, q = idx & 7;
        *(uint4*)&Xl[node * XS + q * 8] = d;
    }
    float dv[16];
    #pragma unroll
    for (int nt = 0; nt < 16; ++nt) dv[nt] = ws[WDINV + nt * 16 + c0];
    __syncthreads();
    // ---- GEMM1: wave w owns j-tile mt=w; A-frags via broadcast-pair b32 ----
    bf16x8 af[8];
    {
        int colb = w * 16 + (c0 & 14);
        int sh = (c0 & 1) * 16;
        int rbase = (lane >> 4) * 8;
        #pragma unroll
        for (int ks = 0; ks < 8; ++ks) {
            unsigned wd[8];
            #pragma unroll
            for (int j = 0; j < 8; ++j)
                wd[j] = *(const unsigned*)&Xl[(ks * 32 + rbase + j) * XS + colb];
            union { bf16x8 v; unsigned u[4]; } tmp;
            #pragma unroll
            for (int q = 0; q < 4; ++q)
                tmp.u[q] = ((wd[2 * q] >> sh) & 0xffffu)
                         | (((wd[2 * q + 1] >> sh) & 0xffffu) << 16);
            af[ks] = tmp.v;
        }
    }
    f32x4 acc[16];
    #pragma unroll
    for (int nt = 0; nt < 16; ++nt) {
        #pragma unroll
        for (int r = 0; r < 4; ++r) acc[nt][r] = 0.f;
    }
    {
        const bf16x8* bsrc = (const bf16x8*)(ws + WAFRG);
        #pragma unroll
        for (int nt = 0; nt < 16; ++nt) {
            bf16x8 bf[8];
            #pragma unroll
            for (int ks = 0; ks < 8; ++ks)
                bf[ks] = bsrc[(nt * 8 + ks) * 64 + lane];
            #pragma unroll
            for (int ks = 0; ks < 8; ++ks)
                acc[nt] = __builtin_amdgcn_mfma_f32_16x16x32_bf16(
                    af[ks], bf[ks], acc[nt], 0, 0, 0);
        }
    }
    {
        int j0 = w * 16 + quad * 4;
        #pragma unroll
        for (int nt = 0; nt < 16; ++nt) {
            float d = dv[nt];
            unsigned p0 = f2bf(acc[nt][0] * d) | (f2bf(acc[nt][1] * d) << 16);
            unsigned p1 = f2bf(acc[nt][2] * d) | (f2bf(acc[nt][3] * d) << 16);
            int v = nt * 16 + c0;
            *(uint2*)&Sl[v * XS + j0] = make_uint2(p0, p1);
        }
    }
    __syncthreads();
    // ---- GEMM2: wave w owns row-tiles 4w..4w+3 ----
    bf16x8 bq[16];
    {
        const bf16x8* qf = (const bf16x8*)(ws + WQFRAG);
        #pragma unroll
        for (int i = 0; i < 16; ++i) bq[i] = qf[i * 64 + lane];
    }
    const float* bias = ws + WBIAS;
    #pragma unroll
    for (int rti = 0; rti < 4; ++rti) {
        int rt = w * 4 + rti;
        const short* xr = &Xl[(rt * 16 + c0) * XS];
        const short* sr = &Sl[(rt * 16 + c0) * XS];
        bf16x8 ax0 = *(const bf16x8*)(xr + q8);
        bf16x8 ax1 = *(const bf16x8*)(xr + 32 + q8);
        bf16x8 as0 = *(const bf16x8*)(sr + q8);
        bf16x8 as1 = *(const bf16x8*)(sr + 32 + q8);
        #pragma unroll
        for (int ct = 0; ct < 4; ++ct) {
            f32x4 a2;
            #pragma unroll
            for (int r = 0; r < 4; ++r)
                a2[r] = bias[(rt * 16 + quad * 4 + r) * 64 + ct * 16 + c0];
            a2 = __builtin_amdgcn_mfma_f32_16x16x32_bf16(ax0, bq[ct],      a2, 0, 0, 0);
            a2 = __builtin_amdgcn_mfma_f32_16x16x32_bf16(ax1, bq[4 + ct],  a2, 0, 0, 0);
            a2 = __builtin_amdgcn_mfma_f32_16x16x32_bf16(as0, bq[8 + ct],  a2, 0, 0, 0);
            a2 = __builtin_amdgcn_mfma_f32_16x16x32_bf16(as1, bq[12 + ct], a2, 0, 0, 0);
            #pragma unroll
            for (int r = 0; r < 4; ++r)
                out[((size_t)tg * 256 + rt * 16 + quad * 4 + r) * 64 + ct * 16 + c0]
                    = a2[r];
        }
    }
    // ---- rare correction (cnt==0 -> W2a, not W2a+Q) ----
    int v = tid;
    float sel = ws[WSEL + v];
    if (__syncthreads_or(sel < 0.5f)) {
        if (sel < 0.5f) {
            float* og = out + ((size_t)tg * 256 + v) * 64;
            #pragma unroll
            for (int jc = 0; jc < 4; ++jc) {
                float corr[16];
                #pragma unroll
                for (int j = 0; j < 16; ++j) corr[j] = 0.f;
                #pragma unroll
                for (int k = 0; k < 64; ++k) {
                    unsigned hv = (unsigned short)Xl[v * XS + k];
                    float xk = __uint_as_float(hv << 16);
                    const float* Q = ws + WRM + k * 64 + jc * 16;
                    #pragma unroll
                    for (int j = 0; j < 16; ++j) corr[j] += xk * Q[j];
                }
                #pragma unroll
                for (int j = 0; j < 16; ++j) og[jc * 16 + j] -= corr[j];
            }
        }
    }
}

extern "C" void kernel_launch(void* const* d_in, const int* in_sizes, int n_in,
                              void* d_out, int out_size, void* d_ws, size_t ws_size,
                              hipStream_t stream) {
    const float* aqi  = (const float*)d_in[0];
    const int*   conn = (const int*)d_in[1];
    const float* cw   = (const float*)d_in[2];
    const float* embW = (const float*)d_in[3];
    const float* embB = (const float*)d_in[4];
    const float* Wih  = (const float*)d_in[5];
    const float* Whh  = (const float*)d_in[6];
    const float* bih  = (const float*)d_in[7];
    const float* bhh  = (const float*)d_in[8];
    const float* m1W  = (const float*)d_in[9];
    const float* m1b  = (const float*)d_in[10];
    const float* m2W  = (const float*)d_in[11];
    const float* m2b  = (const float*)d_in[12];
    float* ws  = (float*)d_ws;
    float* out = (float*)d_out;

    k_main<<<dim3(265), dim3(256), 0, stream>>>(aqi, conn, cw, Wih, embW, embB,
                                                bih, bhh, Whh, m1W, m1b, m2W,
                                                m2b, ws);
    k_graph<<<dim3(T_), dim3(256), 0, stream>>>(ws, out);
}